// Round 9
// baseline (908.951 us; speedup 1.0000x reference)
//
#include <hip/hip_runtime.h>

#define BATCH 512
#define TT 256
#define HH 256
#define HOR 22

__device__ __forceinline__ float rcp_(float x) { return __builtin_amdgcn_rcpf(x); }
__device__ __forceinline__ float sigmoidf_(float x) { return rcp_(1.0f + __expf(-x)); }
__device__ __forceinline__ float tanhf_(float x) {
    float e = __expf(-2.0f * fabsf(x));
    float t = (1.0f - e) * rcp_(1.0f + e);
    return copysignf(t, x);
}
__device__ __forceinline__ unsigned f2bf_rne(float f) {
    unsigned u = __float_as_uint(f);
    unsigned lsb = (u >> 16) & 1u;
    return (u + 0x7FFFu + lsb) >> 16;
}

// v_dot2_f32_bf16: acc += a.lo*b.lo + a.hi*b.hi (packed bf16 pairs). VGPR srcs only (R7).
#define DOT2(acc, a, b) asm("v_dot2_f32_bf16 %0, %1, %2, %0" : "+v"(acc) : "v"(a), "v"(b))

// VGPR pin (residency within the 128-reg clamp)
#define PIN(v) asm volatile("" : "+v"(v))
#define PIN4(q) { PIN((q).x); PIN((q).y); PIN((q).z); PIN((q).w); }

// AGPR storage: explicit accvgpr write/read (legal VALU ops on gfx950)
#define AWRITE(ag, v) asm volatile("v_accvgpr_write_b32 %0, %1" : "=a"(ag) : "v"(v))
#define AREAD(v, ag)  asm volatile("v_accvgpr_read_b32 %0, %1" : "=v"(v) : "a"(ag))

// DPP cross-lane (VALU pipe, no LDS)
#define DPPF(x, ctrl) __int_as_float(__builtin_amdgcn_update_dpp(0, __float_as_int(x), (ctrl), 0xF, 0xF, true))
#define RCOMB(out, a, b, p, ctrl)                          \
    {                                                      \
        float _ta = (a) + DPPF((a), ctrl);                 \
        float _tb = (b) + DPPF((b), ctrl);                 \
        (out) = (p) ? _tb : _ta;                           \
    }
#define RCOMB4(out, a, b, p2v)                                         \
    {                                                                  \
        float _xa = (p2v) ? DPPF((a), 0x114) : DPPF((a), 0x104);       \
        float _xb = (p2v) ? DPPF((b), 0x114) : DPPF((b), 0x104);       \
        float _ta = (a) + _xa;                                         \
        float _tb = (b) + _xb;                                         \
        (out) = (p2v) ? _tb : _ta;                                     \
    }

// ---------------- prep: transpose U matrices to packed-bf16 rows UT[col][kpair] ----------------
__global__ __launch_bounds__(256) void prep_kernel(const float* __restrict__ Uz,
                                                   const float* __restrict__ Ur,
                                                   const float* __restrict__ Uh,
                                                   unsigned* __restrict__ UzT,
                                                   unsigned* __restrict__ UrT,
                                                   unsigned* __restrict__ UhT) {
    int tid = blockIdx.x * 256 + threadIdx.x;   // 0 .. 98303
    int m  = tid >> 15;
    int r  = tid & 32767;
    int j  = r & 255;
    int kp = r >> 8;
    const float* src = (m == 0) ? Uz : (m == 1) ? Ur : Uh;
    unsigned*    dst = (m == 0) ? UzT : (m == 1) ? UrT : UhT;
    float a0 = src[(2 * kp)     * HH + j];
    float a1 = src[(2 * kp + 1) * HH + j];
    dst[j * (HH / 2) + kp] = f2bf_rne(a0) | (f2bf_rne(a1) << 16);
}

// ---------------- persistent GRU: 1 WG = 2 batch rows, 512 thr = 64 col-quads x 8 K-slices ----
// Storage split (R8 lesson: 512-thr WG VGPR budget is a hard 128):
//   Uz -> 64 pinned VGPRs; Ur -> 64 AGPRs (accvgpr read per use); Uh -> 128 KB LDS.
// Zero per-step global traffic by construction.
__global__ __launch_bounds__(512) __attribute__((amdgpu_waves_per_eu(2, 2))) void gru_kernel(
    const float* __restrict__ x,
    const float* __restrict__ Wzw, const float* __restrict__ Wzb, const float* __restrict__ Uzb,
    const float* __restrict__ Wrw, const float* __restrict__ Wrb, const float* __restrict__ Urb,
    const float* __restrict__ Whw, const float* __restrict__ Whb, const float* __restrict__ Uhb,
    const float* __restrict__ Wgw, const float* __restrict__ Wgb,
    const float* __restrict__ om_raw, const float* __restrict__ al_raw,
    const float* __restrict__ be_raw, const float* __restrict__ gam,
    const float* __restrict__ fc1w, const float* __restrict__ fc1b,
    const float* __restrict__ fc2w, const float* __restrict__ fc2b,
    const unsigned* __restrict__ UzT, const unsigned* __restrict__ UrT,
    const unsigned* __restrict__ UhT,
    float* __restrict__ out) {
    __shared__ unsigned Uh_lds[32768];                    // 128 KB: Uh as [kp*256 + col]
    __shared__ __align__(16) unsigned char hS[2 * 640];   // bf16 h, 80B-padded 32-col slices
    __shared__ __align__(16) unsigned char rhS[2 * 640];  // bf16 r*h
    __shared__ float xs[2][TT];
    __shared__ float hid[2][HH];

    const int t  = threadIdx.x;
    const int s  = t & 7;          // K-slice 0..7
    const int cq = t >> 3;         // column quad 0..63
    const bool p0 = (t & 1), p1 = (t & 2), p2 = (t & 4);
    const int c_own   = t & 3;             // owned column within quad
    const int b_own   = (t >> 2) & 1;      // owned batch
    const int col_own = 4 * cq + c_own;
    const int b0 = blockIdx.x * 2;

    // ---- Uz resident in VGPRs: 4 cols x 4 uint4 = 64 dwords ----
    uint4 wz[4][4];
#pragma unroll
    for (int l = 0; l < 4; ++l) {
        const uint4* pz = (const uint4*)(UzT + (4 * cq + l) * 128 + s * 16);
#pragma unroll
        for (int u = 0; u < 4; ++u) wz[l][u] = pz[u];
    }
#pragma unroll
    for (int l = 0; l < 4; ++l)
#pragma unroll
        for (int u = 0; u < 4; ++u) PIN4(wz[l][u]);

    // ---- Ur resident in AGPRs: 64 dwords ----
    unsigned ra[4][4][4];
#pragma unroll
    for (int l = 0; l < 4; ++l) {
        const uint4* pr = (const uint4*)(UrT + (4 * cq + l) * 128 + s * 16);
#pragma unroll
        for (int u = 0; u < 4; ++u) {
            uint4 v = pr[u];
            AWRITE(ra[l][u][0], v.x);
            AWRITE(ra[l][u][1], v.y);
            AWRITE(ra[l][u][2], v.z);
            AWRITE(ra[l][u][3], v.w);
        }
    }

    // ---- Uh into LDS: Uh_lds[kp*256+col] = UhT[col*128+kp], coalesced reads ----
#pragma unroll 4
    for (int i = 0; i < 64; ++i) {
        int g = t + 512 * i;
        Uh_lds[(g & 127) * 256 + (g >> 7)] = UhT[g];
    }

    // scalar params (uniform)
    const float omega = log1pf(__expf(om_raw[0])) + 1e-6f;
    const float aco   = sigmoidf_(al_raw[0]);
    const float bco   = sigmoidf_(be_raw[0]) * (1.0f - aco * 0.99f);
    const float gma   = gam[0];

    // per-lane (owned-column) params, exact fp32
    const float wz_o = Wzw[col_own], bz_o = Wzb[col_own] + Uzb[col_own];
    const float wr_o = Wrw[col_own], br_o = Wrb[col_own] + Urb[col_own];
    const float wh_o = Whw[col_own], bh_o = Whb[col_own] + Uhb[col_own];
    const float wg_o = Wgw[col_own], bg_o = Wgb[col_own];

    // stage x rows; zero h
    xs[t >> 8][t & 255] = x[(b0 + (t >> 8)) * TT + (t & 255)];
    if (t < 320) ((unsigned*)hS)[t] = 0;

    float h_own = 0.f, z_own = 0.f;
    float eps0 = 1e-6f, sig0 = 1e-6f, eps1 = 1e-6f, sig1 = 1e-6f;
    __syncthreads();

    const int sl_off = s * 80;
    const int wr_off = (col_own >> 5) * 40 + (col_own & 31);

    const uint4* uhp = ((const uint4*)Uh_lds) + s * 1024 + cq;               // + i*64 per kp
    const uint4* rq0 = (const uint4*)(((const unsigned*)rhS) + s * 20);      // 16 rh dwords
    const uint4* rq1 = (const uint4*)(((const unsigned*)(rhS + 640)) + s * 20);

    for (int tt = 0; tt < TT; ++tt) {
        const float x0 = xs[0][tt];
        const float x1 = xs[1][tt];
        const float g0 = omega + aco * eps0 + bco * sig0;
        const float g1 = omega + aco * eps1 + bco * sig1;
        eps0 = x0 * x0; sig0 = g0;
        eps1 = x1 * x1; sig1 = g1;
        const float x_o = p2 ? x1 : x0;
        const float g_o = p2 ? g1 : g0;

        // ---- phase A: z (Uz from VGPR) and r (Ur from AGPR) dots, h streamed 2-deep ----
        const uint4* h0p = (const uint4*)(hS + sl_off);
        const uint4* h1p = (const uint4*)(hS + 640 + sl_off);
        float az[4][2], ar[4][2];
#pragma unroll
        for (int l = 0; l < 4; ++l) { az[l][0] = 0.f; az[l][1] = 0.f; ar[l][0] = 0.f; ar[l][1] = 0.f; }
        {
            uint4 hqa = h0p[0], hqb = h1p[0];
#pragma unroll
            for (int u = 0; u < 4; ++u) {
                uint4 ca = hqa, cb = hqb;
                if (u < 3) { hqa = h0p[u + 1]; hqb = h1p[u + 1]; }
#pragma unroll
                for (int l = 0; l < 4; ++l) {
                    uint4 a = wz[l][u];
                    DOT2(az[l][0], a.x, ca.x); DOT2(az[l][0], a.y, ca.y);
                    DOT2(az[l][0], a.z, ca.z); DOT2(az[l][0], a.w, ca.w);
                    DOT2(az[l][1], a.x, cb.x); DOT2(az[l][1], a.y, cb.y);
                    DOT2(az[l][1], a.z, cb.z); DOT2(az[l][1], a.w, cb.w);
                    unsigned t0, t1, t2, t3;
                    AREAD(t0, ra[l][u][0]);
                    DOT2(ar[l][0], t0, ca.x); DOT2(ar[l][1], t0, cb.x);
                    AREAD(t1, ra[l][u][1]);
                    DOT2(ar[l][0], t1, ca.y); DOT2(ar[l][1], t1, cb.y);
                    AREAD(t2, ra[l][u][2]);
                    DOT2(ar[l][0], t2, ca.z); DOT2(ar[l][1], t2, cb.z);
                    AREAD(t3, ra[l][u][3]);
                    DOT2(ar[l][0], t3, ca.w); DOT2(ar[l][1], t3, cb.w);
                }
            }
        }
        // ---- DPP reduce-scatter ----
        float z1a[2][2], r1a[2][2];
        RCOMB(z1a[0][0], az[0][0], az[1][0], p0, 0xB1);
        RCOMB(z1a[0][1], az[0][1], az[1][1], p0, 0xB1);
        RCOMB(z1a[1][0], az[2][0], az[3][0], p0, 0xB1);
        RCOMB(z1a[1][1], az[2][1], az[3][1], p0, 0xB1);
        RCOMB(r1a[0][0], ar[0][0], ar[1][0], p0, 0xB1);
        RCOMB(r1a[0][1], ar[0][1], ar[1][1], p0, 0xB1);
        RCOMB(r1a[1][0], ar[2][0], ar[3][0], p0, 0xB1);
        RCOMB(r1a[1][1], ar[2][1], ar[3][1], p0, 0xB1);
        float z2a[2], r2a[2];
        RCOMB(z2a[0], z1a[0][0], z1a[1][0], p1, 0x4E);
        RCOMB(z2a[1], z1a[0][1], z1a[1][1], p1, 0x4E);
        RCOMB(r2a[0], r1a[0][0], r1a[1][0], p1, 0x4E);
        RCOMB(r2a[1], r1a[0][1], r1a[1][1], p1, 0x4E);
        float accZ, accR;
        RCOMB4(accZ, z2a[0], z2a[1], p2);
        RCOMB4(accR, r2a[0], r2a[1], p2);

        z_own = sigmoidf_(accZ + x_o * wz_o + bz_o);
        const float r = sigmoidf_(accR + x_o * wr_o + br_o);
        ((unsigned short*)(rhS + b_own * 640))[wr_off] = (unsigned short)f2bf_rne(r * h_own);
        __syncthreads();

        // ---- phase B: candidate gate, Uh from LDS (b128 of 4 col-weights per kp) ----
        float ah[4][2];
#pragma unroll
        for (int l = 0; l < 4; ++l) { ah[l][0] = 0.f; ah[l][1] = 0.f; }
#pragma unroll
        for (int half = 0; half < 2; ++half) {
            uint4 qa0 = rq0[2 * half], qb0 = rq0[2 * half + 1];
            uint4 qa1 = rq1[2 * half], qb1 = rq1[2 * half + 1];
            unsigned r0v[8] = {qa0.x, qa0.y, qa0.z, qa0.w, qb0.x, qb0.y, qb0.z, qb0.w};
            unsigned r1v[8] = {qa1.x, qa1.y, qa1.z, qa1.w, qb1.x, qb1.y, qb1.z, qb1.w};
#pragma unroll
            for (int i = 0; i < 8; ++i) {
                uint4 w4 = uhp[(8 * half + i) * 64];
                DOT2(ah[0][0], w4.x, r0v[i]); DOT2(ah[1][0], w4.y, r0v[i]);
                DOT2(ah[2][0], w4.z, r0v[i]); DOT2(ah[3][0], w4.w, r0v[i]);
                DOT2(ah[0][1], w4.x, r1v[i]); DOT2(ah[1][1], w4.y, r1v[i]);
                DOT2(ah[2][1], w4.z, r1v[i]); DOT2(ah[3][1], w4.w, r1v[i]);
            }
        }
        float h1a[2][2];
        RCOMB(h1a[0][0], ah[0][0], ah[1][0], p0, 0xB1);
        RCOMB(h1a[0][1], ah[0][1], ah[1][1], p0, 0xB1);
        RCOMB(h1a[1][0], ah[2][0], ah[3][0], p0, 0xB1);
        RCOMB(h1a[1][1], ah[2][1], ah[3][1], p0, 0xB1);
        float h2a[2];
        RCOMB(h2a[0], h1a[0][0], h1a[1][0], p1, 0x4E);
        RCOMB(h2a[1], h1a[0][1], h1a[1][1], p1, 0x4E);
        float accH;
        RCOMB4(accH, h2a[0], h2a[1], p2);

        const float htld = tanhf_(accH + x_o * wh_o + bh_o);
        const float hh   = (1.f - z_own) * htld + z_own * h_own;
        const float hn   = tanhf_(hh + gma * (g_o * wg_o + bg_o));
        h_own = hn;
        ((unsigned short*)(hS + b_own * 640))[wr_off] = (unsigned short)f2bf_rne(hn);
        __syncthreads();
    }

    // ---- stash exact fp32 h (reuse xs) ----
    xs[b_own][col_own] = h_own;
    __syncthreads();

    // ---- head: hid = relu(h @ fc1 + b1) ----
    {
        const int b = t >> 8, j = t & 255;
        float acc = 0.f;
#pragma unroll 4
        for (int k = 0; k < HH; ++k) acc += xs[b][k] * fc1w[k * HH + j];
        hid[b][j] = fmaxf(acc + fc1b[j], 0.f);
    }
    __syncthreads();

    // ---- head: nn_scale / vol ----
    if (t < 2 * HOR) {
        const int b = t / HOR;
        const int c = t % HOR;
        float acc = fc2b[c];
        for (int k = 0; k < HH; ++k) acc += hid[b][k] * fc2w[k * HOR + c];
        const float sp = log1pf(__expf(acc));
        const float sg = b ? sig1 : sig0;
        const float vb = sqrtf(sg + 1e-8f);
        float vol = vb * (1.0f + sp);
        vol = fminf(fmaxf(vol, 0.01f), 10.0f);
        out[(b0 + b) * HOR + c] = vol;
    }
    if (t == 0) out[BATCH * HOR + b0]     = sig0;
    if (t == 1) out[BATCH * HOR + b0 + 1] = sig1;
}

extern "C" void kernel_launch(void* const* d_in, const int* in_sizes, int n_in,
                              void* d_out, int out_size, void* d_ws, size_t ws_size,
                              hipStream_t stream) {
    const float* x    = (const float*)d_in[0];
    const float* Wzw  = (const float*)d_in[1];
    const float* Wzb  = (const float*)d_in[2];
    const float* Uzw  = (const float*)d_in[3];
    const float* Uzb  = (const float*)d_in[4];
    const float* Wrw  = (const float*)d_in[5];
    const float* Wrb  = (const float*)d_in[6];
    const float* Urw  = (const float*)d_in[7];
    const float* Urb  = (const float*)d_in[8];
    const float* Whw  = (const float*)d_in[9];
    const float* Whb  = (const float*)d_in[10];
    const float* Uhw  = (const float*)d_in[11];
    const float* Uhb  = (const float*)d_in[12];
    const float* Wgw  = (const float*)d_in[13];
    const float* Wgb  = (const float*)d_in[14];
    const float* om   = (const float*)d_in[15];
    const float* al   = (const float*)d_in[16];
    const float* be   = (const float*)d_in[17];
    const float* ga   = (const float*)d_in[18];
    const float* fc1w = (const float*)d_in[19];
    const float* fc1b = (const float*)d_in[20];
    const float* fc2w = (const float*)d_in[21];
    const float* fc2b = (const float*)d_in[22];

    unsigned* UzT = (unsigned*)d_ws;       // 32768 uints each
    unsigned* UrT = UzT + 32768;
    unsigned* UhT = UrT + 32768;

    prep_kernel<<<384, 256, 0, stream>>>(Uzw, Urw, Uhw, UzT, UrT, UhT);
    gru_kernel<<<256, 512, 0, stream>>>(x, Wzw, Wzb, Uzb, Wrw, Wrb, Urb, Whw, Whb, Uhb,
                                        Wgw, Wgb, om, al, be, ga, fc1w, fc1b, fc2w, fc2b,
                                        UzT, UrT, UhT, (float*)d_out);
}

// Round 10
// 843.833 us; speedup vs baseline: 1.0772x; 1.0772x over previous
//
#include <hip/hip_runtime.h>

#define BATCH 512
#define TT 256
#define HH 256
#define HOR 22

__device__ __forceinline__ float rcp_(float x) { return __builtin_amdgcn_rcpf(x); }
__device__ __forceinline__ float sigmoidf_(float x) { return rcp_(1.0f + __expf(-x)); }
__device__ __forceinline__ float tanhf_(float x) {
    float e = __expf(-2.0f * fabsf(x));
    float t = (1.0f - e) * rcp_(1.0f + e);
    return copysignf(t, x);
}
__device__ __forceinline__ unsigned f2bf_rne(float f) {
    unsigned u = __float_as_uint(f);
    unsigned lsb = (u >> 16) & 1u;
    return (u + 0x7FFFu + lsb) >> 16;
}

// v_dot2_f32_bf16: acc += a.lo*b.lo + a.hi*b.hi (packed bf16 pairs). VGPR srcs only (R7).
#define DOT2(acc, a, b) asm("v_dot2_f32_bf16 %0, %1, %2, %0" : "+v"(acc) : "v"(a), "v"(b))

// VGPR pin (residency within the 128-reg clamp)
#define PIN(v) asm volatile("" : "+v"(v))
#define PIN4(q) { PIN((q).x); PIN((q).y); PIN((q).z); PIN((q).w); }

// AGPR storage: explicit accvgpr write/read (legal VALU ops on gfx950)
#define AWRITE(ag, v) asm volatile("v_accvgpr_write_b32 %0, %1" : "=a"(ag) : "v"(v))
#define AREAD(v, ag)  asm volatile("v_accvgpr_read_b32 %0, %1" : "=v"(v) : "a"(ag))

// DPP cross-lane (VALU pipe, no LDS)
#define DPPF(x, ctrl) __int_as_float(__builtin_amdgcn_update_dpp(0, __float_as_int(x), (ctrl), 0xF, 0xF, true))
#define RCOMB(out, a, b, p, ctrl)                          \
    {                                                      \
        float _ta = (a) + DPPF((a), ctrl);                 \
        float _tb = (b) + DPPF((b), ctrl);                 \
        (out) = (p) ? _tb : _ta;                           \
    }
#define RCOMB4(out, a, b, p2v)                                         \
    {                                                                  \
        float _xa = (p2v) ? DPPF((a), 0x114) : DPPF((a), 0x104);       \
        float _xb = (p2v) ? DPPF((b), 0x114) : DPPF((b), 0x104);       \
        float _ta = (a) + _xa;                                         \
        float _tb = (b) + _xb;                                         \
        (out) = (p2v) ? _tb : _ta;                                     \
    }

// ---------------- prep: transpose U matrices to packed-bf16 rows UT[col][kpair] ----------------
__global__ __launch_bounds__(256) void prep_kernel(const float* __restrict__ Uz,
                                                   const float* __restrict__ Ur,
                                                   const float* __restrict__ Uh,
                                                   unsigned* __restrict__ UzT,
                                                   unsigned* __restrict__ UrT,
                                                   unsigned* __restrict__ UhT) {
    int tid = blockIdx.x * 256 + threadIdx.x;   // 0 .. 98303
    int m  = tid >> 15;
    int r  = tid & 32767;
    int j  = r & 255;
    int kp = r >> 8;
    const float* src = (m == 0) ? Uz : (m == 1) ? Ur : Uh;
    unsigned*    dst = (m == 0) ? UzT : (m == 1) ? UrT : UhT;
    float a0 = src[(2 * kp)     * HH + j];
    float a1 = src[(2 * kp + 1) * HH + j];
    dst[j * (HH / 2) + kp] = f2bf_rne(a0) | (f2bf_rne(a1) << 16);
}

// ---------------- persistent GRU: 1 WG = 2 batch rows, 512 thr = 64 col-quads x 8 K-slices ----
// Storage split: Uz -> 64 pinned VGPRs; Ur -> 64 AGPRs; Uh -> 128 KB LDS in
// idx-major/thread-minor layout Uh2[idx*512+t] (R9's kp-major layout gave 8-way
// bank conflicts: the s*1024-dword term is bank-invariant -> 1.1e8 conflict cycles).
// Stride-1 wave b128 = conflict-free (m134). Zero per-step global traffic.
__global__ __launch_bounds__(512) __attribute__((amdgpu_waves_per_eu(2, 2))) void gru_kernel(
    const float* __restrict__ x,
    const float* __restrict__ Wzw, const float* __restrict__ Wzb, const float* __restrict__ Uzb,
    const float* __restrict__ Wrw, const float* __restrict__ Wrb, const float* __restrict__ Urb,
    const float* __restrict__ Whw, const float* __restrict__ Whb, const float* __restrict__ Uhb,
    const float* __restrict__ Wgw, const float* __restrict__ Wgb,
    const float* __restrict__ om_raw, const float* __restrict__ al_raw,
    const float* __restrict__ be_raw, const float* __restrict__ gam,
    const float* __restrict__ fc1w, const float* __restrict__ fc1b,
    const float* __restrict__ fc2w, const float* __restrict__ fc2b,
    const unsigned* __restrict__ UzT, const unsigned* __restrict__ UrT,
    const unsigned* __restrict__ UhT,
    float* __restrict__ out) {
    __shared__ uint4 Uh2[16 * 512];                       // 128 KB, Uh2[idx*512+t]
    __shared__ __align__(16) unsigned char hS[2 * 640];   // bf16 h, 80B-padded 32-col slices
    __shared__ __align__(16) unsigned char rhS[2 * 640];  // bf16 r*h
    __shared__ float xs[2][TT];
    __shared__ float hid[2][HH];

    const int t  = threadIdx.x;
    const int s  = t & 7;          // K-slice 0..7
    const int cq = t >> 3;         // column quad 0..63
    const bool p0 = (t & 1), p1 = (t & 2), p2 = (t & 4);
    const int c_own   = t & 3;             // owned column within quad
    const int b_own   = (t >> 2) & 1;      // owned batch
    const int col_own = 4 * cq + c_own;
    const int b0 = blockIdx.x * 2;

    // ---- Uz resident in VGPRs: 4 cols x 4 uint4 = 64 dwords ----
    uint4 wz[4][4];
#pragma unroll
    for (int l = 0; l < 4; ++l) {
        const uint4* pz = (const uint4*)(UzT + (4 * cq + l) * 128 + s * 16);
#pragma unroll
        for (int u = 0; u < 4; ++u) wz[l][u] = pz[u];
    }
#pragma unroll
    for (int l = 0; l < 4; ++l)
#pragma unroll
        for (int u = 0; u < 4; ++u) PIN4(wz[l][u]);

    // ---- Ur resident in AGPRs: 64 dwords ----
    unsigned ra[4][4][4];
#pragma unroll
    for (int l = 0; l < 4; ++l) {
        const uint4* pr = (const uint4*)(UrT + (4 * cq + l) * 128 + s * 16);
#pragma unroll
        for (int u = 0; u < 4; ++u) {
            uint4 v = pr[u];
            AWRITE(ra[l][u][0], v.x);
            AWRITE(ra[l][u][1], v.y);
            AWRITE(ra[l][u][2], v.z);
            AWRITE(ra[l][u][3], v.w);
        }
    }

    // ---- Uh into LDS, per-thread gather into idx-major layout (one-time) ----
#pragma unroll 4
    for (int idx = 0; idx < 16; ++idx) {
        const int kp = s * 16 + idx;
        uint4 v;
        v.x = UhT[(4 * cq + 0) * 128 + kp];
        v.y = UhT[(4 * cq + 1) * 128 + kp];
        v.z = UhT[(4 * cq + 2) * 128 + kp];
        v.w = UhT[(4 * cq + 3) * 128 + kp];
        Uh2[idx * 512 + t] = v;
    }

    // scalar params (uniform)
    const float omega = log1pf(__expf(om_raw[0])) + 1e-6f;
    const float aco   = sigmoidf_(al_raw[0]);
    const float bco   = sigmoidf_(be_raw[0]) * (1.0f - aco * 0.99f);
    const float gma   = gam[0];

    // per-lane (owned-column) params, exact fp32
    const float wz_o = Wzw[col_own], bz_o = Wzb[col_own] + Uzb[col_own];
    const float wr_o = Wrw[col_own], br_o = Wrb[col_own] + Urb[col_own];
    const float wh_o = Whw[col_own], bh_o = Whb[col_own] + Uhb[col_own];
    const float wg_o = Wgw[col_own], bg_o = Wgb[col_own];

    // stage x rows; zero h
    xs[t >> 8][t & 255] = x[(b0 + (t >> 8)) * TT + (t & 255)];
    if (t < 320) ((unsigned*)hS)[t] = 0;

    float h_own = 0.f, z_own = 0.f;
    float eps0 = 1e-6f, sig0 = 1e-6f, eps1 = 1e-6f, sig1 = 1e-6f;
    __syncthreads();

    const int sl_off = s * 80;
    const int wr_off = (col_own >> 5) * 40 + (col_own & 31);

    const uint4* uh2p = Uh2 + t;                                             // + idx*512
    const uint4* rq0 = (const uint4*)(((const unsigned*)rhS) + s * 20);      // 16 rh dwords
    const uint4* rq1 = (const uint4*)(((const unsigned*)(rhS + 640)) + s * 20);

    for (int tt = 0; tt < TT; ++tt) {
        const float x0 = xs[0][tt];
        const float x1 = xs[1][tt];
        const float g0 = omega + aco * eps0 + bco * sig0;
        const float g1 = omega + aco * eps1 + bco * sig1;
        eps0 = x0 * x0; sig0 = g0;
        eps1 = x1 * x1; sig1 = g1;
        const float x_o = p2 ? x1 : x0;
        const float g_o = p2 ? g1 : g0;

        // ---- phase A: z (Uz from VGPR) and r (Ur from AGPR) dots, h streamed 2-deep ----
        const uint4* h0p = (const uint4*)(hS + sl_off);
        const uint4* h1p = (const uint4*)(hS + 640 + sl_off);
        float az[4][2], ar[4][2];
#pragma unroll
        for (int l = 0; l < 4; ++l) { az[l][0] = 0.f; az[l][1] = 0.f; ar[l][0] = 0.f; ar[l][1] = 0.f; }
        {
            uint4 hqa = h0p[0], hqb = h1p[0];
#pragma unroll
            for (int u = 0; u < 4; ++u) {
                uint4 ca = hqa, cb = hqb;
                if (u < 3) { hqa = h0p[u + 1]; hqb = h1p[u + 1]; }
#pragma unroll
                for (int l = 0; l < 4; ++l) {
                    uint4 a = wz[l][u];
                    DOT2(az[l][0], a.x, ca.x); DOT2(az[l][0], a.y, ca.y);
                    DOT2(az[l][0], a.z, ca.z); DOT2(az[l][0], a.w, ca.w);
                    DOT2(az[l][1], a.x, cb.x); DOT2(az[l][1], a.y, cb.y);
                    DOT2(az[l][1], a.z, cb.z); DOT2(az[l][1], a.w, cb.w);
                    unsigned t0, t1, t2, t3;
                    AREAD(t0, ra[l][u][0]);
                    DOT2(ar[l][0], t0, ca.x); DOT2(ar[l][1], t0, cb.x);
                    AREAD(t1, ra[l][u][1]);
                    DOT2(ar[l][0], t1, ca.y); DOT2(ar[l][1], t1, cb.y);
                    AREAD(t2, ra[l][u][2]);
                    DOT2(ar[l][0], t2, ca.z); DOT2(ar[l][1], t2, cb.z);
                    AREAD(t3, ra[l][u][3]);
                    DOT2(ar[l][0], t3, ca.w); DOT2(ar[l][1], t3, cb.w);
                }
            }
        }
        // ---- DPP reduce-scatter ----
        float z1a[2][2], r1a[2][2];
        RCOMB(z1a[0][0], az[0][0], az[1][0], p0, 0xB1);
        RCOMB(z1a[0][1], az[0][1], az[1][1], p0, 0xB1);
        RCOMB(z1a[1][0], az[2][0], az[3][0], p0, 0xB1);
        RCOMB(z1a[1][1], az[2][1], az[3][1], p0, 0xB1);
        RCOMB(r1a[0][0], ar[0][0], ar[1][0], p0, 0xB1);
        RCOMB(r1a[0][1], ar[0][1], ar[1][1], p0, 0xB1);
        RCOMB(r1a[1][0], ar[2][0], ar[3][0], p0, 0xB1);
        RCOMB(r1a[1][1], ar[2][1], ar[3][1], p0, 0xB1);
        float z2a[2], r2a[2];
        RCOMB(z2a[0], z1a[0][0], z1a[1][0], p1, 0x4E);
        RCOMB(z2a[1], z1a[0][1], z1a[1][1], p1, 0x4E);
        RCOMB(r2a[0], r1a[0][0], r1a[1][0], p1, 0x4E);
        RCOMB(r2a[1], r1a[0][1], r1a[1][1], p1, 0x4E);
        float accZ, accR;
        RCOMB4(accZ, z2a[0], z2a[1], p2);
        RCOMB4(accR, r2a[0], r2a[1], p2);

        z_own = sigmoidf_(accZ + x_o * wz_o + bz_o);
        const float r = sigmoidf_(accR + x_o * wr_o + br_o);
        ((unsigned short*)(rhS + b_own * 640))[wr_off] = (unsigned short)f2bf_rne(r * h_own);
        __syncthreads();

        // ---- phase B: candidate gate, Uh from LDS (conflict-free stride-1 b128) ----
        float ah[4][2];
#pragma unroll
        for (int l = 0; l < 4; ++l) { ah[l][0] = 0.f; ah[l][1] = 0.f; }
#pragma unroll
        for (int half = 0; half < 2; ++half) {
            uint4 qa0 = rq0[2 * half], qb0 = rq0[2 * half + 1];
            uint4 qa1 = rq1[2 * half], qb1 = rq1[2 * half + 1];
            unsigned r0v[8] = {qa0.x, qa0.y, qa0.z, qa0.w, qb0.x, qb0.y, qb0.z, qb0.w};
            unsigned r1v[8] = {qa1.x, qa1.y, qa1.z, qa1.w, qb1.x, qb1.y, qb1.z, qb1.w};
#pragma unroll
            for (int i = 0; i < 8; ++i) {
                uint4 w4 = uh2p[(8 * half + i) * 512];
                DOT2(ah[0][0], w4.x, r0v[i]); DOT2(ah[1][0], w4.y, r0v[i]);
                DOT2(ah[2][0], w4.z, r0v[i]); DOT2(ah[3][0], w4.w, r0v[i]);
                DOT2(ah[0][1], w4.x, r1v[i]); DOT2(ah[1][1], w4.y, r1v[i]);
                DOT2(ah[2][1], w4.z, r1v[i]); DOT2(ah[3][1], w4.w, r1v[i]);
            }
        }
        float h1a[2][2];
        RCOMB(h1a[0][0], ah[0][0], ah[1][0], p0, 0xB1);
        RCOMB(h1a[0][1], ah[0][1], ah[1][1], p0, 0xB1);
        RCOMB(h1a[1][0], ah[2][0], ah[3][0], p0, 0xB1);
        RCOMB(h1a[1][1], ah[2][1], ah[3][1], p0, 0xB1);
        float h2a[2];
        RCOMB(h2a[0], h1a[0][0], h1a[1][0], p1, 0x4E);
        RCOMB(h2a[1], h1a[0][1], h1a[1][1], p1, 0x4E);
        float accH;
        RCOMB4(accH, h2a[0], h2a[1], p2);

        const float htld = tanhf_(accH + x_o * wh_o + bh_o);
        const float hh   = (1.f - z_own) * htld + z_own * h_own;
        const float hn   = tanhf_(hh + gma * (g_o * wg_o + bg_o));
        h_own = hn;
        ((unsigned short*)(hS + b_own * 640))[wr_off] = (unsigned short)f2bf_rne(hn);
        __syncthreads();
    }

    // ---- stash exact fp32 h (reuse xs) ----
    xs[b_own][col_own] = h_own;
    __syncthreads();

    // ---- head: hid = relu(h @ fc1 + b1) ----
    {
        const int b = t >> 8, j = t & 255;
        float acc = 0.f;
#pragma unroll 4
        for (int k = 0; k < HH; ++k) acc += xs[b][k] * fc1w[k * HH + j];
        hid[b][j] = fmaxf(acc + fc1b[j], 0.f);
    }
    __syncthreads();

    // ---- head: nn_scale / vol ----
    if (t < 2 * HOR) {
        const int b = t / HOR;
        const int c = t % HOR;
        float acc = fc2b[c];
        for (int k = 0; k < HH; ++k) acc += hid[b][k] * fc2w[k * HOR + c];
        const float sp = log1pf(__expf(acc));
        const float sg = b ? sig1 : sig0;
        const float vb = sqrtf(sg + 1e-8f);
        float vol = vb * (1.0f + sp);
        vol = fminf(fmaxf(vol, 0.01f), 10.0f);
        out[(b0 + b) * HOR + c] = vol;
    }
    if (t == 0) out[BATCH * HOR + b0]     = sig0;
    if (t == 1) out[BATCH * HOR + b0 + 1] = sig1;
}

extern "C" void kernel_launch(void* const* d_in, const int* in_sizes, int n_in,
                              void* d_out, int out_size, void* d_ws, size_t ws_size,
                              hipStream_t stream) {
    const float* x    = (const float*)d_in[0];
    const float* Wzw  = (const float*)d_in[1];
    const float* Wzb  = (const float*)d_in[2];
    const float* Uzw  = (const float*)d_in[3];
    const float* Uzb  = (const float*)d_in[4];
    const float* Wrw  = (const float*)d_in[5];
    const float* Wrb  = (const float*)d_in[6];
    const float* Urw  = (const float*)d_in[7];
    const float* Urb  = (const float*)d_in[8];
    const float* Whw  = (const float*)d_in[9];
    const float* Whb  = (const float*)d_in[10];
    const float* Uhw  = (const float*)d_in[11];
    const float* Uhb  = (const float*)d_in[12];
    const float* Wgw  = (const float*)d_in[13];
    const float* Wgb  = (const float*)d_in[14];
    const float* om   = (const float*)d_in[15];
    const float* al   = (const float*)d_in[16];
    const float* be   = (const float*)d_in[17];
    const float* ga   = (const float*)d_in[18];
    const float* fc1w = (const float*)d_in[19];
    const float* fc1b = (const float*)d_in[20];
    const float* fc2w = (const float*)d_in[21];
    const float* fc2b = (const float*)d_in[22];

    unsigned* UzT = (unsigned*)d_ws;       // 32768 uints each
    unsigned* UrT = UzT + 32768;
    unsigned* UhT = UrT + 32768;

    prep_kernel<<<384, 256, 0, stream>>>(Uzw, Urw, Uhw, UzT, UrT, UhT);
    gru_kernel<<<256, 512, 0, stream>>>(x, Wzw, Wzb, Uzb, Wrw, Wrb, Urb, Whw, Whb, Uhb,
                                        Wgw, Wgb, om, al, be, ga, fc1w, fc1b, fc2w, fc2b,
                                        UzT, UrT, UhT, (float*)d_out);
}